// Round 10
// baseline (824.073 us; speedup 1.0000x reference)
//
#include <hip/hip_runtime.h>
#include <cstdint>
#include <cstddef>

using u16 = unsigned short;
using bf16x8 = __attribute__((ext_vector_type(8))) short;
using f32x16 = __attribute__((ext_vector_type(16))) float;

__device__ __forceinline__ u16 f2bf(float f) {
  unsigned u = __float_as_uint(f);
  u += 0x7fffu + ((u >> 16) & 1u);
  return (u16)(u >> 16);
}
__device__ __forceinline__ float bf2f(u16 h) {
  return __uint_as_float(((unsigned)h) << 16);
}

__device__ __forceinline__ void gload_lds16(const void* g, void* l) {
  auto gp = reinterpret_cast<const __attribute__((address_space(1))) char*>(
      reinterpret_cast<uintptr_t>(g));
  auto lp = reinterpret_cast<__attribute__((address_space(3))) char*>(
      reinterpret_cast<uintptr_t>(l));
  __builtin_amdgcn_global_load_lds(gp, lp, 16, 0, 0);
}

// ---------- weight transpose + downcast: W f32[din][dout] -> WT bf16[dout][din]
__global__ __launch_bounds__(256) void transpose_to_bf16(
    const float* __restrict__ W, u16* __restrict__ WT, int din, int dout) {
  __shared__ float tile[32][33];
  const int j0 = blockIdx.x * 32;   // dout
  const int i0 = blockIdx.y * 32;   // din
  const int tx = threadIdx.x & 31;
  const int ty = threadIdx.x >> 5;  // 0..7
#pragma unroll
  for (int k = 0; k < 32; k += 8)
    tile[ty + k][tx] = W[(size_t)(i0 + ty + k) * dout + (j0 + tx)];
  __syncthreads();
#pragma unroll
  for (int k = 0; k < 32; k += 8)
    WT[(size_t)(j0 + ty + k) * din + (i0 + tx)] = f2bf(tile[tx][ty + k]);
}

// ---------- rmsnorm f32 -> bf16, one block per row of 1024
__global__ __launch_bounds__(256) void rmsnorm_kernel(
    const float* __restrict__ x, const float* __restrict__ g, u16* __restrict__ xn) {
  const int row = blockIdx.x;
  const float4 v = ((const float4*)(x + (size_t)row * 1024))[threadIdx.x];
  float ss = v.x * v.x + v.y * v.y + v.z * v.z + v.w * v.w;
#pragma unroll
  for (int off = 32; off > 0; off >>= 1) ss += __shfl_down(ss, off, 64);
  __shared__ float red[4];
  if ((threadIdx.x & 63) == 0) red[threadIdx.x >> 6] = ss;
  __syncthreads();
  const float rs = rsqrtf((red[0] + red[1] + red[2] + red[3]) * (1.f / 1024.f) + 1e-6f);
  const float4 gv = ((const float4*)g)[threadIdx.x];
  ushort4 o;
  o.x = f2bf(v.x * rs * gv.x);
  o.y = f2bf(v.y * rs * gv.y);
  o.z = f2bf(v.z * rs * gv.z);
  o.w = f2bf(v.w * rs * gv.w);
  ((ushort4*)(xn + (size_t)row * 1024))[threadIdx.x] = o;
}

// ---------- chunked linear-recurrence scan: h[l] = sig(-dt)*h[l-1] + sig(dt)*sig(lnz)
__global__ __launch_bounds__(256) void scan_pass1(
    const u16* __restrict__ dt, const u16* __restrict__ lnz,
    float* __restrict__ P, float* __restrict__ S) {
  const int blk = blockIdx.x;              // B*64*4 = 1024 blocks
  const int dblk = blk & 3;
  const int chunk = (blk >> 2) & 63;
  const int b = blk >> 8;
  const int d = dblk * 256 + threadIdx.x;
  const size_t base = ((size_t)b * 4096 + (size_t)chunk * 64) * 1024 + d;
  float p = 1.f, s = 0.f;
#pragma unroll 8
  for (int l = 0; l < 64; ++l) {
    const float dtv = bf2f(dt[base + (size_t)l * 1024]);
    const float zv = bf2f(lnz[base + (size_t)l * 1024]);
    const float a = 1.f / (1.f + __expf(dtv));        // sigmoid(-dt)
    const float zs = 1.f / (1.f + __expf(-zv));       // sigmoid(lnz_pre)
    const float in = (1.f - a) * zs;
    p *= a;
    s = a * s + in;
  }
  const size_t o = ((size_t)b * 64 + chunk) * 1024 + d;
  P[o] = p;
  S[o] = s;
}

__global__ __launch_bounds__(256) void scan_pass2(
    const float* __restrict__ P, const float* __restrict__ S,
    const float* __restrict__ hidden, float* __restrict__ hin) {
  const int idx = blockIdx.x * 256 + threadIdx.x;  // 0..4095
  const int b = idx >> 10, d = idx & 1023;
  float h = hidden[idx];
#pragma unroll 8
  for (int c = 0; c < 64; ++c) {
    const size_t o = ((size_t)b * 64 + c) * 1024 + d;
    hin[o] = h;
    h = P[o] * h + S[o];
  }
}

__global__ __launch_bounds__(256) void scan_pass3(
    const u16* __restrict__ dt, const u16* __restrict__ lnz,
    const float* __restrict__ hin, float* __restrict__ h_out, u16* __restrict__ hbf) {
  const int blk = blockIdx.x;
  const int dblk = blk & 3;
  const int chunk = (blk >> 2) & 63;
  const int b = blk >> 8;
  const int d = dblk * 256 + threadIdx.x;
  const size_t base = ((size_t)b * 4096 + (size_t)chunk * 64) * 1024 + d;
  float h = hin[((size_t)b * 64 + chunk) * 1024 + d];
#pragma unroll 4
  for (int l = 0; l < 64; ++l) {
    const float dtv = bf2f(dt[base + (size_t)l * 1024]);
    const float zv = bf2f(lnz[base + (size_t)l * 1024]);
    const float a = 1.f / (1.f + __expf(dtv));
    const float zs = 1.f / (1.f + __expf(-zv));
    h = a * h + (1.f - a) * zs;
    h_out[base + (size_t)l * 1024] = h;
    hbf[base + (size_t)l * 1024] = f2bf(h);
  }
}

// ---------- 256x256 GEMM on mfma_f32_32x32x16_bf16: C = A[M][K] @ B^T (bf16).
// R6 relaxed 2-barrier schedule, ring of 10 half-tile LDS slots (160 KiB),
// lead = 3 half-tiles, counted vmcnt(6). Per wave per K-tile: 32 MFMA
// (16x16x32 needed 64), 24 ds_read_b128 (same bytes).
// Register fix vs R9: bR[2][4] holds BOTH nt fragments for the whole tile
// (MMAQ(1,0) consumes bR[0] after MMAQ(0,1) consumed bR[1] — R9 clobbered it).
// A/B frag (contiguous k, analog of the verified 16x16x32 mapping):
//   row = lane&31, k = ks*16 + (lane>>5)*8 + e  -> byte ks*32 + (lane>>5)*16.
// C/D: col = lane&31, row = (reg&3)+8*(reg>>2)+4*(lane>>5)  [guide m74/m101].
// EPI: 5 = fused3: bf16 outs {outH=dt, outH2=lnz, outH3=yg}, row stride 1024
//      2 = f32 out = (acc+b)*silu(gate bf16) + resid
//      6 = bf16 out = silu(acc+b)
//      7 = bf16 out = (acc+b)*bf2f(gate)   (gate may alias outH: in-place)
//      4 = f32 out = acc + b + outF (in-place residual add)
template <int EPI>
__global__ __launch_bounds__(512, 2) void gemm256(
    const u16* __restrict__ A, const u16* __restrict__ B,
    const float* __restrict__ bias, const u16* __restrict__ gate,
    const float* __restrict__ resid, float* __restrict__ outF,
    u16* __restrict__ outH, u16* __restrict__ outH2, u16* __restrict__ outH3,
    int ntx, int N, int K) {
  constexpr int SLOT = 16384;
  constexpr int LDSZ = 10 * SLOT;
  const int tid = threadIdx.x;
  const int lane = tid & 63;
  const int wid = tid >> 6;
  const int wr = wid >> 2;   // 0..1 -> A half
  const int wc = wid & 3;    // 0..3 -> 64-col strip; wc>>1 -> B half

  // XCD-aware swizzle (grid %8==0 for all our launches)
  const int nwg = gridDim.x;
  int id = blockIdx.x;
  id = (id & 7) * (nwg >> 3) + (id >> 3);
  const int m0 = (id / ntx) * 256;
  const int n0 = (id % ntx) * 256;

  __shared__ __align__(16) char lds[LDSZ];

  f32x16 acc[4][2];   // [mt over wave's 128 rows][nt over wave's 64 cols]
#pragma unroll
  for (int m = 0; m < 4; ++m)
#pragma unroll
    for (int n = 0; n < 2; ++n)
#pragma unroll
      for (int j = 0; j < 16; ++j) acc[m][n][j] = 0.f;

  bf16x8 aR[2][4];   // [mt within current QM][ks]
  bf16x8 bR[2][4];   // [nt][ks] — BOTH nt live across the whole K-tile

  // ---- hoisted LDS read offsets (relative to slot base) ----
  int aOff[2][4], bOff[2][4];
  {
    const int lq = (lane >> 5) << 4;
#pragma unroll
    for (int mt = 0; mt < 2; ++mt) {
      const int hr = mt * 32 + (lane & 31);
#pragma unroll
      for (int ks = 0; ks < 4; ++ks)
        aOff[mt][ks] = hr * 128 + ((ks * 32 + lq) ^ ((hr & 7) << 4));
    }
#pragma unroll
    for (int nt = 0; nt < 2; ++nt) {
      const int hr = (wc & 1) * 64 + nt * 32 + (lane & 31);
#pragma unroll
      for (int ks = 0; ks < 4; ++ks)
        bOff[nt][ks] = hr * 128 + ((ks * 32 + lq) ^ ((hr & 7) << 4));
    }
  }

  // ---- hoisted stage addressing ----
  const int row0 = tid >> 3;                               // 0..63
  const int kb0  = ((tid & 7) * 16) ^ ((row0 & 7) << 4);   // inverse-swizzled src byte
  const size_t dRow = (size_t)128 * K;                     // +64 rows (bytes)
  const char* pA0 = (const char*)A + (size_t)(m0 + row0) * K * 2 + kb0;
  const char* pA1 = pA0 + (size_t)256 * K;                 // +128 rows
  const char* pB0 = (const char*)B + (size_t)(n0 + row0) * K * 2 + kb0;
  const char* pB1 = pB0 + (size_t)256 * K;
  const int ldst = tid * 16;                               // LDS offset within slot

#define STAGE(PTR, SB)                                                        \
  {                                                                           \
    gload_lds16(PTR, lds + (SB) + ldst);                                      \
    gload_lds16(PTR + dRow, lds + (SB) + ldst + 8192);                        \
    PTR += 128;                                                               \
  }

#define READA(SAB, QM)                                                        \
  _Pragma("unroll") for (int mt = 0; mt < 2; ++mt)                            \
  _Pragma("unroll") for (int ks = 0; ks < 4; ++ks)                            \
    aR[mt][ks] = *(const bf16x8*)(lds + (SAB) + aOff[mt][ks] + (QM) * 8192);

#define READB(SBB, NT)                                                        \
  _Pragma("unroll") for (int ks = 0; ks < 4; ++ks)                            \
    bR[NT][ks] = *(const bf16x8*)(lds + (SBB) + bOff[NT][ks]);

#define MMAQ(QM, QN)                                                          \
  __builtin_amdgcn_s_setprio(1);                                              \
  _Pragma("unroll") for (int mt = 0; mt < 2; ++mt)                            \
  _Pragma("unroll") for (int ks = 0; ks < 4; ++ks)                            \
      acc[(QM) * 2 + mt][QN] = __builtin_amdgcn_mfma_f32_32x32x16_bf16(       \
          aR[mt][ks], bR[QN][ks], acc[(QM) * 2 + mt][QN], 0, 0, 0);           \
  __builtin_amdgcn_s_setprio(0);

  const int NT2 = K >> 6;

  // prologue: halves 0..6 -> slots 0..6 (tile0 complete + tile1 A0,A1,B0)
  STAGE(pA0, 0 * SLOT);
  STAGE(pA1, 1 * SLOT);
  STAGE(pB0, 2 * SLOT);
  STAGE(pB1, 3 * SLOT);
  STAGE(pA0, 4 * SLOT);
  STAGE(pA1, 5 * SLOT);
  STAGE(pB0, 6 * SLOT);
  asm volatile("s_waitcnt vmcnt(6)" ::: "memory");   // tile0 resident, 3 halves in flight
  __builtin_amdgcn_s_barrier();

  int iA = wr;             // slot of this wave's A half, advances +4 mod 10
  int iB = 2 + (wc >> 1);  // slot of this wave's B half
  int iS = 7;              // stage slot for B1(t+1)

  for (int t = 0; t < NT2; ++t) {
    const int sAb = __builtin_amdgcn_readfirstlane(iA * SLOT);
    const int sBb = __builtin_amdgcn_readfirstlane(iB * SLOT);
    int s0 = iS * SLOT;
    int s1 = s0 + SLOT; if (s1 >= LDSZ) s1 -= LDSZ;
    int s2 = s1 + SLOT; if (s2 >= LDSZ) s2 -= LDSZ;
    int s3 = s2 + SLOT; if (s3 >= LDSZ) s3 -= LDSZ;
    const bool st0 = (t <= NT2 - 2);     // stage B1 of tile t+1
    const bool st123 = (t <= NT2 - 3);   // stage A0/A1/B0 of tile t+2
    // free-flowing span: reads + 32 MFMA, 2 barriers/K-tile (R6 audit)
    READA(sAb, 0);
    READB(sBb, 0);
    READB(sBb, 1);
    if (st0) STAGE(pB1, s0);
    MMAQ(0, 0);
    if (st123) STAGE(pA0, s1);
    MMAQ(0, 1);
    READA(sAb, 1);
    if (st123) STAGE(pA1, s2);
    MMAQ(1, 0);
    __builtin_amdgcn_s_barrier();
    if (st123) STAGE(pB0, s3);
    MMAQ(1, 1);
    if (t < NT2 - 2) asm volatile("s_waitcnt vmcnt(6)" ::: "memory");
    else             asm volatile("s_waitcnt vmcnt(0)" ::: "memory");
    __builtin_amdgcn_s_barrier();
    iA += 4; if (iA >= 10) iA -= 10;
    iB += 4; if (iB >= 10) iB -= 10;
    iS += 4; if (iS >= 10) iS -= 10;
  }

  // epilogue: C/D layout col = lane&31, row = (reg&3) + 8*(reg>>2) + 4*(lane>>5)
#pragma unroll
  for (int mt = 0; mt < 4; ++mt) {
#pragma unroll
    for (int nt = 0; nt < 2; ++nt) {
      const int col = n0 + wc * 64 + nt * 32 + (lane & 31);
#pragma unroll
      for (int reg = 0; reg < 16; ++reg) {
        const int row = m0 + wr * 128 + mt * 32 + (reg & 3) + 8 * (reg >> 2) + 4 * (lane >> 5);
        const float v = acc[mt][nt][reg] + bias[col];
        if constexpr (EPI == 5) {
          const int rg = col >> 10;                     // block-uniform
          const size_t o = (size_t)row * 1024 + (col & 1023);
          if (rg == 0) outH[o] = f2bf(v);
          else if (rg == 1) outH2[o] = f2bf(v);
          else outH3[o] = f2bf(v);
        } else {
          const size_t o = (size_t)row * N + col;
          if constexpr (EPI == 2) {
            const float gt = bf2f(gate[o]);
            outF[o] = v * (gt / (1.f + __expf(-gt))) + resid[o];
          } else if constexpr (EPI == 6) {
            outH[o] = f2bf(v / (1.f + __expf(-v)));
          } else if constexpr (EPI == 7) {
            outH[o] = f2bf(v * bf2f(gate[o]));          // gate==outH ok (RAW per elem)
          } else if constexpr (EPI == 4) {
            outF[o] = v + outF[o];
          }
        }
      }
    }
  }
#undef STAGE
#undef READA
#undef READB
#undef MMAQ
}

extern "C" void kernel_launch(void* const* d_in, const int* in_sizes, int n_in,
                              void* d_out, int out_size, void* d_ws, size_t ws_size,
                              hipStream_t stream) {
  const float* x      = (const float*)d_in[0];
  const float* hidden = (const float*)d_in[1];
  const float* w_ln_z = (const float*)d_in[2];
  const float* b_ln_z = (const float*)d_in[3];
  const float* w_dt   = (const float*)d_in[4];
  const float* b_dt   = (const float*)d_in[5];
  const float* w_y    = (const float*)d_in[6];
  const float* b_y    = (const float*)d_in[7];
  const float* w_yg   = (const float*)d_in[8];
  const float* b_yg   = (const float*)d_in[9];
  const float* w_ff   = (const float*)d_in[10];
  const float* b_ff   = (const float*)d_in[11];
  const float* w_ffg  = (const float*)d_in[12];
  const float* b_ffg  = (const float*)d_in[13];
  const float* w_ffo  = (const float*)d_in[14];
  const float* b_ffo  = (const float*)d_in[15];
  const float* g_sio  = (const float*)d_in[16];
  const float* g_ffn  = (const float*)d_in[17];

  char* ws = (char*)d_ws;
  const size_t MB = 1ull << 20;
  u16*   WT_cat = (u16*)(ws + 0 * MB);      // 6 MiB  [3072][1024] (dt|lnz|yg)
  u16*   WT_y   = (u16*)(ws + 8 * MB);      // 2 MiB
  u16*   WT_ff  = (u16*)(ws + 10 * MB);     // 8 MiB  [4096][1024]
  u16*   WT_ffg = (u16*)(ws + 18 * MB);     // 8 MiB
  u16*   WT_ffo = (u16*)(ws + 26 * MB);     // 8 MiB  [1024][4096]
  float* b_cat  = (float*)(ws + 34 * MB);   // 12 KiB [3072]
  u16*   xn     = (u16*)(ws + 36 * MB);     // 32 MiB [16384][1024] bf16
  u16*   dt16   = (u16*)(ws + 68 * MB);     // 32 MiB bf16
  u16*   lnzb   = (u16*)(ws + 100 * MB);    // 32 MiB
  u16*   ygb    = (u16*)(ws + 132 * MB);    // 32 MiB
  u16*   hbf    = (u16*)(ws + 164 * MB);    // 32 MiB
  float* Pc     = (float*)(ws + 196 * MB);  // 1 MiB
  float* Sc     = (float*)(ws + 197 * MB);  // 1 MiB
  float* hin    = (float*)(ws + 198 * MB);  // 1 MiB
  u16*   gs     = (u16*)(ws + 68 * MB);     // 128 MiB overlay [16384][4096]
  // peak ws usage: 199 MiB

  float* x_out = (float*)d_out;
  float* h_out = (float*)d_out + (size_t)4 * 4096 * 1024;

  const int M = 16384, D = 1024, F = 4096;
  const dim3 tb(256);

  transpose_to_bf16<<<dim3(32, 32), tb, 0, stream>>>(w_dt, WT_cat, D, D);
  transpose_to_bf16<<<dim3(32, 32), tb, 0, stream>>>(w_ln_z, WT_cat + 1024 * 1024, D, D);
  transpose_to_bf16<<<dim3(32, 32), tb, 0, stream>>>(w_yg, WT_cat + 2 * 1024 * 1024, D, D);
  transpose_to_bf16<<<dim3(32, 32), tb, 0, stream>>>(w_y, WT_y, D, D);
  transpose_to_bf16<<<dim3(128, 32), tb, 0, stream>>>(w_ff, WT_ff, D, F);
  transpose_to_bf16<<<dim3(128, 32), tb, 0, stream>>>(w_ffg, WT_ffg, D, F);
  transpose_to_bf16<<<dim3(32, 128), tb, 0, stream>>>(w_ffo, WT_ffo, F, D);
  (void)hipMemcpyAsync(b_cat, b_dt, D * 4, hipMemcpyDeviceToDevice, stream);
  (void)hipMemcpyAsync(b_cat + 1024, b_ln_z, D * 4, hipMemcpyDeviceToDevice, stream);
  (void)hipMemcpyAsync(b_cat + 2048, b_yg, D * 4, hipMemcpyDeviceToDevice, stream);

  rmsnorm_kernel<<<M, tb, 0, stream>>>(x, g_sio, xn);

  // fused dt|lnz|yg GEMM: N=3072
  gemm256<5><<<dim3(12 * 64), 512, 0, stream>>>(xn, WT_cat, b_cat, nullptr, nullptr,
                                                nullptr, dt16, lnzb, ygb, 12, 3072, D);

  scan_pass1<<<1024, tb, 0, stream>>>(dt16, lnzb, Pc, Sc);
  scan_pass2<<<16, tb, 0, stream>>>(Pc, Sc, hidden, hin);
  scan_pass3<<<1024, tb, 0, stream>>>(dt16, lnzb, hin, h_out, hbf);

  // x1 = (h@w_y + b_y) * silu(yg) + x
  gemm256<2><<<dim3(4 * 64), 512, 0, stream>>>(hbf, WT_y, b_y, ygb, x,
                                               x_out, nullptr, nullptr, nullptr, 4, D, D);

  rmsnorm_kernel<<<M, tb, 0, stream>>>(x_out, g_ffn, xn);

  // gs = silu(xn@w_ffg + b_ffg)
  gemm256<6><<<dim3(16 * 64), 512, 0, stream>>>(xn, WT_ffg, b_ffg, nullptr, nullptr,
                                                nullptr, gs, nullptr, nullptr, 16, F, D);
  // gs = (xn@w_ff + b_ff) * gs   (in-place gated mul)
  gemm256<7><<<dim3(16 * 64), 512, 0, stream>>>(xn, WT_ff, b_ff, gs, nullptr,
                                                nullptr, gs, nullptr, nullptr, 16, F, D);
  // x_out += gs@w_ffo + b_ffo
  gemm256<4><<<dim3(4 * 64), 512, 0, stream>>>(gs, WT_ffo, b_ffo, nullptr, nullptr,
                                               x_out, nullptr, nullptr, nullptr, 4, D, F);
}

// Round 11
// 780.285 us; speedup vs baseline: 1.0561x; 1.0561x over previous
//
#include <hip/hip_runtime.h>
#include <cstdint>
#include <cstddef>

using u16 = unsigned short;
using bf16x8 = __attribute__((ext_vector_type(8))) short;
using f32x4  = __attribute__((ext_vector_type(4))) float;

__device__ __forceinline__ u16 f2bf(float f) {
  unsigned u = __float_as_uint(f);
  u += 0x7fffu + ((u >> 16) & 1u);
  return (u16)(u >> 16);
}
__device__ __forceinline__ float bf2f(u16 h) {
  return __uint_as_float(((unsigned)h) << 16);
}

__device__ __forceinline__ void gload_lds16(const void* g, void* l) {
  auto gp = reinterpret_cast<const __attribute__((address_space(1))) char*>(
      reinterpret_cast<uintptr_t>(g));
  auto lp = reinterpret_cast<__attribute__((address_space(3))) char*>(
      reinterpret_cast<uintptr_t>(l));
  __builtin_amdgcn_global_load_lds(gp, lp, 16, 0, 0);
}

// ---------- weight transpose + downcast: W f32[din][dout] -> WT bf16[dout][din]
__global__ __launch_bounds__(256) void transpose_to_bf16(
    const float* __restrict__ W, u16* __restrict__ WT, int din, int dout) {
  __shared__ float tile[32][33];
  const int j0 = blockIdx.x * 32;   // dout
  const int i0 = blockIdx.y * 32;   // din
  const int tx = threadIdx.x & 31;
  const int ty = threadIdx.x >> 5;  // 0..7
#pragma unroll
  for (int k = 0; k < 32; k += 8)
    tile[ty + k][tx] = W[(size_t)(i0 + ty + k) * dout + (j0 + tx)];
  __syncthreads();
#pragma unroll
  for (int k = 0; k < 32; k += 8)
    WT[(size_t)(j0 + ty + k) * din + (i0 + tx)] = f2bf(tile[tx][ty + k]);
}

// ---------- rmsnorm f32 -> bf16, one block per row of 1024
__global__ __launch_bounds__(256) void rmsnorm_kernel(
    const float* __restrict__ x, const float* __restrict__ g, u16* __restrict__ xn) {
  const int row = blockIdx.x;
  const float4 v = ((const float4*)(x + (size_t)row * 1024))[threadIdx.x];
  float ss = v.x * v.x + v.y * v.y + v.z * v.z + v.w * v.w;
#pragma unroll
  for (int off = 32; off > 0; off >>= 1) ss += __shfl_down(ss, off, 64);
  __shared__ float red[4];
  if ((threadIdx.x & 63) == 0) red[threadIdx.x >> 6] = ss;
  __syncthreads();
  const float rs = rsqrtf((red[0] + red[1] + red[2] + red[3]) * (1.f / 1024.f) + 1e-6f);
  const float4 gv = ((const float4*)g)[threadIdx.x];
  ushort4 o;
  o.x = f2bf(v.x * rs * gv.x);
  o.y = f2bf(v.y * rs * gv.y);
  o.z = f2bf(v.z * rs * gv.z);
  o.w = f2bf(v.w * rs * gv.w);
  ((ushort4*)(xn + (size_t)row * 1024))[threadIdx.x] = o;
}

// ---------- chunked linear-recurrence scan: h[l] = sig(-dt)*h[l-1] + sig(dt)*sig(lnz)
__global__ __launch_bounds__(256) void scan_pass1(
    const u16* __restrict__ dt, const u16* __restrict__ lnz,
    float* __restrict__ P, float* __restrict__ S) {
  const int blk = blockIdx.x;              // B*64*4 = 1024 blocks
  const int dblk = blk & 3;
  const int chunk = (blk >> 2) & 63;
  const int b = blk >> 8;
  const int d = dblk * 256 + threadIdx.x;
  const size_t base = ((size_t)b * 4096 + (size_t)chunk * 64) * 1024 + d;
  float p = 1.f, s = 0.f;
#pragma unroll 8
  for (int l = 0; l < 64; ++l) {
    const float dtv = bf2f(dt[base + (size_t)l * 1024]);
    const float zv = bf2f(lnz[base + (size_t)l * 1024]);
    const float a = 1.f / (1.f + __expf(dtv));        // sigmoid(-dt)
    const float zs = 1.f / (1.f + __expf(-zv));       // sigmoid(lnz_pre)
    const float in = (1.f - a) * zs;
    p *= a;
    s = a * s + in;
  }
  const size_t o = ((size_t)b * 64 + chunk) * 1024 + d;
  P[o] = p;
  S[o] = s;
}

__global__ __launch_bounds__(256) void scan_pass2(
    const float* __restrict__ P, const float* __restrict__ S,
    const float* __restrict__ hidden, float* __restrict__ hin) {
  const int idx = blockIdx.x * 256 + threadIdx.x;  // 0..4095
  const int b = idx >> 10, d = idx & 1023;
  float h = hidden[idx];
#pragma unroll 8
  for (int c = 0; c < 64; ++c) {
    const size_t o = ((size_t)b * 64 + c) * 1024 + d;
    hin[o] = h;
    h = P[o] * h + S[o];
  }
}

__global__ __launch_bounds__(256) void scan_pass3(
    const u16* __restrict__ dt, const u16* __restrict__ lnz,
    const float* __restrict__ hin, float* __restrict__ h_out, u16* __restrict__ hbf) {
  const int blk = blockIdx.x;
  const int dblk = blk & 3;
  const int chunk = (blk >> 2) & 63;
  const int b = blk >> 8;
  const int d = dblk * 256 + threadIdx.x;
  const size_t base = ((size_t)b * 4096 + (size_t)chunk * 64) * 1024 + d;
  float h = hin[((size_t)b * 64 + chunk) * 1024 + d];
#pragma unroll 4
  for (int l = 0; l < 64; ++l) {
    const float dtv = bf2f(dt[base + (size_t)l * 1024]);
    const float zv = bf2f(lnz[base + (size_t)l * 1024]);
    const float a = 1.f / (1.f + __expf(dtv));
    const float zs = 1.f / (1.f + __expf(-zv));
    h = a * h + (1.f - a) * zs;
    h_out[base + (size_t)l * 1024] = h;
    hbf[base + (size_t)l * 1024] = f2bf(h);
  }
}

// ---------- 256x256 GEMM, m201-discipline 8-phase: C = A[M][K] @ B^T (bf16).
// 16x16x32 MFMA (conflict-free with the (row&7)<<4 swizzle — 32x32 regressed,
// R10: inherent 4-way read conflict). 8 waves (2Mx4N), per-wave 128x64 out,
// BK=64, ring of 10 half-tile LDS slots (160 KiB), counted vmcnt(6).
// Phase discipline per the verified m201 template:
//   {ds_reads + 1 STAGE} -> [lgkmcnt(8) if 12 reads] -> s_barrier ->
//   s_waitcnt lgkmcnt(0) -> setprio(1) 16 MFMA setprio(0) -> s_barrier
// Reads service during the barrier wait; explicit post-barrier lgkm(0) is the
// template's wait placement (R3/R4 left it to the compiler).
// Slot layout identical to R4 (ring audit there; passed).
// EPI: 5 = fused3: bf16 outs {outH=dt, outH2=lnz, outH3=yg}, row stride 1024
//      2 = f32 out = (acc+b)*silu(gate bf16) + resid
//      6 = bf16 out = silu(acc+b)
//      7 = bf16 out = (acc+b)*bf2f(gate)   (gate may alias outH: in-place)
//      4 = f32 out = acc + b + outF (in-place residual add)
template <int EPI>
__global__ __launch_bounds__(512, 2) void gemm256(
    const u16* __restrict__ A, const u16* __restrict__ B,
    const float* __restrict__ bias, const u16* __restrict__ gate,
    const float* __restrict__ resid, float* __restrict__ outF,
    u16* __restrict__ outH, u16* __restrict__ outH2, u16* __restrict__ outH3,
    int ntx, int N, int K) {
  constexpr int SLOT = 16384;
  constexpr int LDSZ = 10 * SLOT;
  const int tid = threadIdx.x;
  const int lane = tid & 63;
  const int wid = tid >> 6;
  const int wr = wid >> 2;   // 0..1 -> A half
  const int wc = wid & 3;    // 0..3 -> 64-col strip; wc>>1 -> B half

  // XCD-aware swizzle (grid %8==0 for all our launches)
  const int nwg = gridDim.x;
  int id = blockIdx.x;
  id = (id & 7) * (nwg >> 3) + (id >> 3);
  const int m0 = (id / ntx) * 256;
  const int n0 = (id % ntx) * 256;

  __shared__ __align__(16) char lds[LDSZ];

  f32x4 acc[8][4];
#pragma unroll
  for (int m = 0; m < 8; ++m)
#pragma unroll
    for (int n = 0; n < 4; ++n) acc[m][n] = (f32x4){0.f, 0.f, 0.f, 0.f};

  bf16x8 aR[4][2], bR[4][2];

  // ---- hoisted LDS read offsets (relative to slot base) ----
  int aOff[4][2], bOff[2][2];
  {
    const int lq = (lane >> 4) << 4;
#pragma unroll
    for (int m = 0; m < 4; ++m) {
      const int hr = m * 16 + (lane & 15);
#pragma unroll
      for (int k = 0; k < 2; ++k)
        aOff[m][k] = hr * 128 + ((k * 64 + lq) ^ ((hr & 7) << 4));
    }
#pragma unroll
    for (int n = 0; n < 2; ++n) {
      const int hr = (wc & 1) * 64 + n * 16 + (lane & 15);
#pragma unroll
      for (int k = 0; k < 2; ++k)
        bOff[n][k] = hr * 128 + ((k * 64 + lq) ^ ((hr & 7) << 4));
    }
  }

  // ---- hoisted stage addressing ----
  const int row0 = tid >> 3;                               // 0..63
  const int kb0  = ((tid & 7) * 16) ^ ((row0 & 7) << 4);   // inverse-swizzled src byte
  const size_t dRow = (size_t)128 * K;                     // +64 rows (bytes)
  const char* pA0 = (const char*)A + (size_t)(m0 + row0) * K * 2 + kb0;
  const char* pA1 = pA0 + (size_t)256 * K;                 // +128 rows
  const char* pB0 = (const char*)B + (size_t)(n0 + row0) * K * 2 + kb0;
  const char* pB1 = pB0 + (size_t)256 * K;
  const int ldst = tid * 16;                               // LDS offset within slot

#define STAGE(PTR, SB)                                                        \
  {                                                                           \
    gload_lds16(PTR, lds + (SB) + ldst);                                      \
    gload_lds16(PTR + dRow, lds + (SB) + ldst + 8192);                        \
    PTR += 128;                                                               \
  }

#define READA(SAB, QM)                                                        \
  _Pragma("unroll") for (int m = 0; m < 4; ++m)                               \
  _Pragma("unroll") for (int k = 0; k < 2; ++k)                               \
    aR[m][k] = *(const bf16x8*)(lds + (SAB) + aOff[m][k] + (QM) * 8192);

#define READB(SBB, NP)                                                        \
  _Pragma("unroll") for (int n = 0; n < 2; ++n)                               \
  _Pragma("unroll") for (int k = 0; k < 2; ++k)                               \
    bR[(NP) + n][k] = *(const bf16x8*)(lds + (SBB) + bOff[n][k] + (NP) * 2048);

#define MMAQ(QM, QN)                                                          \
  __builtin_amdgcn_s_setprio(1);                                              \
  _Pragma("unroll") for (int m = 0; m < 4; ++m)                               \
  _Pragma("unroll") for (int n = 0; n < 2; ++n)                               \
  _Pragma("unroll") for (int k = 0; k < 2; ++k)                               \
      acc[(QM) * 4 + m][(QN) * 2 + n] = __builtin_amdgcn_mfma_f32_16x16x32_bf16( \
          aR[m][k], bR[(QN) * 2 + n][k], acc[(QM) * 4 + m][(QN) * 2 + n], 0, 0, 0); \
  __builtin_amdgcn_s_setprio(0);

#define LGKM0 asm volatile("s_waitcnt lgkmcnt(0)" ::: "memory")

  const int NT = K >> 6;

  // prologue: halves 0..6 -> slots 0..6 (tile0 complete + tile1 A0,A1,B0)
  STAGE(pA0, 0 * SLOT);
  STAGE(pA1, 1 * SLOT);
  STAGE(pB0, 2 * SLOT);
  STAGE(pB1, 3 * SLOT);
  STAGE(pA0, 4 * SLOT);
  STAGE(pA1, 5 * SLOT);
  STAGE(pB0, 6 * SLOT);
  asm volatile("s_waitcnt vmcnt(6)" ::: "memory");   // tile0 resident, 3 halves in flight
  __builtin_amdgcn_s_barrier();

  int iA = wr;             // slot of this wave's A half, advances +4 mod 10
  int iB = 2 + (wc >> 1);  // slot of this wave's B half
  int iS = 7;              // stage slot for B1(t+1)

  for (int t = 0; t < NT; ++t) {
    const int sAb = __builtin_amdgcn_readfirstlane(iA * SLOT);
    const int sBb = __builtin_amdgcn_readfirstlane(iB * SLOT);
    int s0 = iS * SLOT;
    int s1 = s0 + SLOT; if (s1 >= LDSZ) s1 -= LDSZ;
    int s2 = s1 + SLOT; if (s2 >= LDSZ) s2 -= LDSZ;
    int s3 = s2 + SLOT; if (s3 >= LDSZ) s3 -= LDSZ;
    const bool st0 = (t <= NT - 2);     // stage B1 of tile t+1
    const bool st123 = (t <= NT - 3);   // stage A0/A1/B0 of tile t+2

    // phase 0: 12 reads, 1 stage
    READA(sAb, 0);
    READB(sBb, 0);
    if (st0) STAGE(pB1, s0);
    asm volatile("s_waitcnt lgkmcnt(8)" ::: "memory");  // 12 issued -> first 4 landed
    __builtin_amdgcn_s_barrier();
    LGKM0;
    MMAQ(0, 0);
    __builtin_amdgcn_s_barrier();
    // phase 1: 4 reads, 1 stage
    READB(sBb, 2);
    if (st123) STAGE(pA0, s1);
    __builtin_amdgcn_s_barrier();
    LGKM0;
    MMAQ(0, 1);
    __builtin_amdgcn_s_barrier();
    // phase 2: 8 reads, 1 stage
    READA(sAb, 1);
    if (st123) STAGE(pA1, s2);
    __builtin_amdgcn_s_barrier();
    LGKM0;
    MMAQ(1, 0);
    __builtin_amdgcn_s_barrier();
    // phase 3: 0 reads, 1 stage; counted vmcnt once per K-tile
    if (st123) STAGE(pB0, s3);
    __builtin_amdgcn_s_barrier();
    MMAQ(1, 1);
    if (t < NT - 2) asm volatile("s_waitcnt vmcnt(6)" ::: "memory");
    else            asm volatile("s_waitcnt vmcnt(0)" ::: "memory");
    __builtin_amdgcn_s_barrier();
    iA += 4; if (iA >= 10) iA -= 10;
    iB += 4; if (iB >= 10) iB -= 10;
    iS += 4; if (iS >= 10) iS -= 10;
  }

  // epilogue: C/D layout col = lane&15, row = (lane>>4)*4 + j
#pragma unroll
  for (int m = 0; m < 8; ++m) {
#pragma unroll
    for (int n = 0; n < 4; ++n) {
      const int col = n0 + wc * 64 + n * 16 + (lane & 15);
#pragma unroll
      for (int j = 0; j < 4; ++j) {
        const int row = m0 + wr * 128 + m * 16 + ((lane >> 4) << 2) + j;
        const float v = acc[m][n][j] + bias[col];
        if constexpr (EPI == 5) {
          const int rg = col >> 10;                     // block-uniform
          const size_t o = (size_t)row * 1024 + (col & 1023);
          if (rg == 0) outH[o] = f2bf(v);
          else if (rg == 1) outH2[o] = f2bf(v);
          else outH3[o] = f2bf(v);
        } else {
          const size_t o = (size_t)row * N + col;
          if constexpr (EPI == 2) {
            const float gt = bf2f(gate[o]);
            outF[o] = v * (gt / (1.f + __expf(-gt))) + resid[o];
          } else if constexpr (EPI == 6) {
            outH[o] = f2bf(v / (1.f + __expf(-v)));
          } else if constexpr (EPI == 7) {
            outH[o] = f2bf(v * bf2f(gate[o]));          // gate==outH ok (RAW per elem)
          } else if constexpr (EPI == 4) {
            outF[o] = v + outF[o];
          }
        }
      }
    }
  }
#undef STAGE
#undef READA
#undef READB
#undef MMAQ
#undef LGKM0
}

extern "C" void kernel_launch(void* const* d_in, const int* in_sizes, int n_in,
                              void* d_out, int out_size, void* d_ws, size_t ws_size,
                              hipStream_t stream) {
  const float* x      = (const float*)d_in[0];
  const float* hidden = (const float*)d_in[1];
  const float* w_ln_z = (const float*)d_in[2];
  const float* b_ln_z = (const float*)d_in[3];
  const float* w_dt   = (const float*)d_in[4];
  const float* b_dt   = (const float*)d_in[5];
  const float* w_y    = (const float*)d_in[6];
  const float* b_y    = (const float*)d_in[7];
  const float* w_yg   = (const float*)d_in[8];
  const float* b_yg   = (const float*)d_in[9];
  const float* w_ff   = (const float*)d_in[10];
  const float* b_ff   = (const float*)d_in[11];
  const float* w_ffg  = (const float*)d_in[12];
  const float* b_ffg  = (const float*)d_in[13];
  const float* w_ffo  = (const float*)d_in[14];
  const float* b_ffo  = (const float*)d_in[15];
  const float* g_sio  = (const float*)d_in[16];
  const float* g_ffn  = (const float*)d_in[17];

  char* ws = (char*)d_ws;
  const size_t MB = 1ull << 20;
  u16*   WT_cat = (u16*)(ws + 0 * MB);      // 6 MiB  [3072][1024] (dt|lnz|yg)
  u16*   WT_y   = (u16*)(ws + 8 * MB);      // 2 MiB
  u16*   WT_ff  = (u16*)(ws + 10 * MB);     // 8 MiB  [4096][1024]
  u16*   WT_ffg = (u16*)(ws + 18 * MB);     // 8 MiB
  u16*   WT_ffo = (u16*)(ws + 26 * MB);     // 8 MiB  [1024][4096]
  float* b_cat  = (float*)(ws + 34 * MB);   // 12 KiB [3072]
  u16*   xn     = (u16*)(ws + 36 * MB);     // 32 MiB [16384][1024] bf16
  u16*   dt16   = (u16*)(ws + 68 * MB);     // 32 MiB bf16
  u16*   lnzb   = (u16*)(ws + 100 * MB);    // 32 MiB
  u16*   ygb    = (u16*)(ws + 132 * MB);    // 32 MiB
  u16*   hbf    = (u16*)(ws + 164 * MB);    // 32 MiB
  float* Pc     = (float*)(ws + 196 * MB);  // 1 MiB
  float* Sc     = (float*)(ws + 197 * MB);  // 1 MiB
  float* hin    = (float*)(ws + 198 * MB);  // 1 MiB
  u16*   gs     = (u16*)(ws + 68 * MB);     // 128 MiB overlay [16384][4096]
  // peak ws usage: 199 MiB

  float* x_out = (float*)d_out;
  float* h_out = (float*)d_out + (size_t)4 * 4096 * 1024;

  const int M = 16384, D = 1024, F = 4096;
  const dim3 tb(256);

  transpose_to_bf16<<<dim3(32, 32), tb, 0, stream>>>(w_dt, WT_cat, D, D);
  transpose_to_bf16<<<dim3(32, 32), tb, 0, stream>>>(w_ln_z, WT_cat + 1024 * 1024, D, D);
  transpose_to_bf16<<<dim3(32, 32), tb, 0, stream>>>(w_yg, WT_cat + 2 * 1024 * 1024, D, D);
  transpose_to_bf16<<<dim3(32, 32), tb, 0, stream>>>(w_y, WT_y, D, D);
  transpose_to_bf16<<<dim3(128, 32), tb, 0, stream>>>(w_ff, WT_ff, D, F);
  transpose_to_bf16<<<dim3(128, 32), tb, 0, stream>>>(w_ffg, WT_ffg, D, F);
  transpose_to_bf16<<<dim3(32, 128), tb, 0, stream>>>(w_ffo, WT_ffo, F, D);
  (void)hipMemcpyAsync(b_cat, b_dt, D * 4, hipMemcpyDeviceToDevice, stream);
  (void)hipMemcpyAsync(b_cat + 1024, b_ln_z, D * 4, hipMemcpyDeviceToDevice, stream);
  (void)hipMemcpyAsync(b_cat + 2048, b_yg, D * 4, hipMemcpyDeviceToDevice, stream);

  rmsnorm_kernel<<<M, tb, 0, stream>>>(x, g_sio, xn);

  // fused dt|lnz|yg GEMM: N=3072
  gemm256<5><<<dim3(12 * 64), 512, 0, stream>>>(xn, WT_cat, b_cat, nullptr, nullptr,
                                                nullptr, dt16, lnzb, ygb, 12, 3072, D);

  scan_pass1<<<1024, tb, 0, stream>>>(dt16, lnzb, Pc, Sc);
  scan_pass2<<<16, tb, 0, stream>>>(Pc, Sc, hidden, hin);
  scan_pass3<<<1024, tb, 0, stream>>>(dt16, lnzb, hin, h_out, hbf);

  // x1 = (h@w_y + b_y) * silu(yg) + x
  gemm256<2><<<dim3(4 * 64), 512, 0, stream>>>(hbf, WT_y, b_y, ygb, x,
                                               x_out, nullptr, nullptr, nullptr, 4, D, D);

  rmsnorm_kernel<<<M, tb, 0, stream>>>(x_out, g_ffn, xn);

  // gs = silu(xn@w_ffg + b_ffg)
  gemm256<6><<<dim3(16 * 64), 512, 0, stream>>>(xn, WT_ffg, b_ffg, nullptr, nullptr,
                                                nullptr, gs, nullptr, nullptr, 16, F, D);
  // gs = (xn@w_ff + b_ff) * gs   (in-place gated mul)
  gemm256<7><<<dim3(16 * 64), 512, 0, stream>>>(xn, WT_ff, b_ff, gs, nullptr,
                                                nullptr, gs, nullptr, nullptr, 16, F, D);
  // x_out += gs@w_ffo + b_ffo
  gemm256<4><<<dim3(4 * 64), 512, 0, stream>>>(gs, WT_ffo, b_ffo, nullptr, nullptr,
                                               x_out, nullptr, nullptr, nullptr, 4, D, F);
}

// Round 12
// 753.121 us; speedup vs baseline: 1.0942x; 1.0361x over previous
//
#include <hip/hip_runtime.h>
#include <cstdint>
#include <cstddef>

using u16 = unsigned short;
using bf16x8 = __attribute__((ext_vector_type(8))) short;
using f32x4  = __attribute__((ext_vector_type(4))) float;

__device__ __forceinline__ u16 f2bf(float f) {
  unsigned u = __float_as_uint(f);
  u += 0x7fffu + ((u >> 16) & 1u);
  return (u16)(u >> 16);
}
__device__ __forceinline__ float bf2f(u16 h) {
  return __uint_as_float(((unsigned)h) << 16);
}

__device__ __forceinline__ void gload_lds16(const void* g, void* l) {
  auto gp = reinterpret_cast<const __attribute__((address_space(1))) char*>(
      reinterpret_cast<uintptr_t>(g));
  auto lp = reinterpret_cast<__attribute__((address_space(3))) char*>(
      reinterpret_cast<uintptr_t>(l));
  __builtin_amdgcn_global_load_lds(gp, lp, 16, 0, 0);
}

// ---------- weight transpose + downcast: W f32[din][dout] -> WT bf16[dout][din]
__global__ __launch_bounds__(256) void transpose_to_bf16(
    const float* __restrict__ W, u16* __restrict__ WT, int din, int dout) {
  __shared__ float tile[32][33];
  const int j0 = blockIdx.x * 32;   // dout
  const int i0 = blockIdx.y * 32;   // din
  const int tx = threadIdx.x & 31;
  const int ty = threadIdx.x >> 5;  // 0..7
#pragma unroll
  for (int k = 0; k < 32; k += 8)
    tile[ty + k][tx] = W[(size_t)(i0 + ty + k) * dout + (j0 + tx)];
  __syncthreads();
#pragma unroll
  for (int k = 0; k < 32; k += 8)
    WT[(size_t)(j0 + ty + k) * din + (i0 + tx)] = f2bf(tile[tx][ty + k]);
}

// ---------- rmsnorm f32 -> bf16, one block per row of 1024
__global__ __launch_bounds__(256) void rmsnorm_kernel(
    const float* __restrict__ x, const float* __restrict__ g, u16* __restrict__ xn) {
  const int row = blockIdx.x;
  const float4 v = ((const float4*)(x + (size_t)row * 1024))[threadIdx.x];
  float ss = v.x * v.x + v.y * v.y + v.z * v.z + v.w * v.w;
#pragma unroll
  for (int off = 32; off > 0; off >>= 1) ss += __shfl_down(ss, off, 64);
  __shared__ float red[4];
  if ((threadIdx.x & 63) == 0) red[threadIdx.x >> 6] = ss;
  __syncthreads();
  const float rs = rsqrtf((red[0] + red[1] + red[2] + red[3]) * (1.f / 1024.f) + 1e-6f);
  const float4 gv = ((const float4*)g)[threadIdx.x];
  ushort4 o;
  o.x = f2bf(v.x * rs * gv.x);
  o.y = f2bf(v.y * rs * gv.y);
  o.z = f2bf(v.z * rs * gv.z);
  o.w = f2bf(v.w * rs * gv.w);
  ((ushort4*)(xn + (size_t)row * 1024))[threadIdx.x] = o;
}

// ---------- chunked linear-recurrence scan: h[l] = sig(-dt)*h[l-1] + sig(dt)*sig(lnz)
__global__ __launch_bounds__(256) void scan_pass1(
    const u16* __restrict__ dt, const u16* __restrict__ lnz,
    float* __restrict__ P, float* __restrict__ S) {
  const int blk = blockIdx.x;              // B*64*4 = 1024 blocks
  const int dblk = blk & 3;
  const int chunk = (blk >> 2) & 63;
  const int b = blk >> 8;
  const int d = dblk * 256 + threadIdx.x;
  const size_t base = ((size_t)b * 4096 + (size_t)chunk * 64) * 1024 + d;
  float p = 1.f, s = 0.f;
#pragma unroll 8
  for (int l = 0; l < 64; ++l) {
    const float dtv = bf2f(dt[base + (size_t)l * 1024]);
    const float zv = bf2f(lnz[base + (size_t)l * 1024]);
    const float a = 1.f / (1.f + __expf(dtv));        // sigmoid(-dt)
    const float zs = 1.f / (1.f + __expf(-zv));       // sigmoid(lnz_pre)
    const float in = (1.f - a) * zs;
    p *= a;
    s = a * s + in;
  }
  const size_t o = ((size_t)b * 64 + chunk) * 1024 + d;
  P[o] = p;
  S[o] = s;
}

__global__ __launch_bounds__(256) void scan_pass2(
    const float* __restrict__ P, const float* __restrict__ S,
    const float* __restrict__ hidden, float* __restrict__ hin) {
  const int idx = blockIdx.x * 256 + threadIdx.x;  // 0..4095
  const int b = idx >> 10, d = idx & 1023;
  float h = hidden[idx];
#pragma unroll 8
  for (int c = 0; c < 64; ++c) {
    const size_t o = ((size_t)b * 64 + c) * 1024 + d;
    hin[o] = h;
    h = P[o] * h + S[o];
  }
}

__global__ __launch_bounds__(256) void scan_pass3(
    const u16* __restrict__ dt, const u16* __restrict__ lnz,
    const float* __restrict__ hin, float* __restrict__ h_out, u16* __restrict__ hbf) {
  const int blk = blockIdx.x;
  const int dblk = blk & 3;
  const int chunk = (blk >> 2) & 63;
  const int b = blk >> 8;
  const int d = dblk * 256 + threadIdx.x;
  const size_t base = ((size_t)b * 4096 + (size_t)chunk * 64) * 1024 + d;
  float h = hin[((size_t)b * 64 + chunk) * 1024 + d];
#pragma unroll 4
  for (int l = 0; l < 64; ++l) {
    const float dtv = bf2f(dt[base + (size_t)l * 1024]);
    const float zv = bf2f(lnz[base + (size_t)l * 1024]);
    const float a = 1.f / (1.f + __expf(dtv));
    const float zs = 1.f / (1.f + __expf(-zv));
    h = a * h + (1.f - a) * zs;
    h_out[base + (size_t)l * 1024] = h;
    hbf[base + (size_t)l * 1024] = f2bf(h);
  }
}

// ---------- 256x128 GEMM, 2 blocks/CU: C = A[M][K] @ B^T, B stored [N][K] bf16.
// TLP design (m97/m114 mechanism): 80 KiB LDS (5 x 16 KiB ring) + <=128 VGPR
// (launch_bounds(512,4)) -> 2 independent blocks/CU, 4 waves/SIMD. Block X's
// MFMA covers block Y's LDS reads / stages / vmcnt(0) drains — no shared
// barriers between blocks.
// 8 waves (2M x 4N): per-wave 128x32 out, acc[8][2] f32x4 = 64 VGPR.
// Half-tiles per K-tile: {B, A0, A1} (16 KiB each). Ring audit (slot = h%5):
//  - stage B(t+1)  -> slot of t-1's A0 (dead: end-barrier of t-1)  [ph0]
//  - stage A0(t+1) -> slot of t-1's A1 (dead)                      [ph1]
//  - stage A1(t+1) -> slot of t's B; B read only in ph0, midbar orders [ph3]
//  - vmcnt(0) + barrier at tile end -> tile t+1 resident.
// 16x16x32 MFMA, conflict-free (row&7)<<4 XOR swizzle. A-quarters (2 m-frags)
// read just-in-time to keep aR at 16 VGPR.
// EPI: 5 = fused3: bf16 outs {outH=dt, outH2=lnz, outH3=yg}, row stride 1024
//      2 = f32 out = (acc+b)*silu(gate bf16) + resid
//      6 = bf16 out = silu(acc+b)
//      7 = bf16 out = (acc+b)*bf2f(gate)   (gate may alias outH: in-place)
//      4 = f32 out = acc + b + outF (in-place residual add)
template <int EPI>
__global__ __launch_bounds__(512, 4) void gemm256(
    const u16* __restrict__ A, const u16* __restrict__ B,
    const float* __restrict__ bias, const u16* __restrict__ gate,
    const float* __restrict__ resid, float* __restrict__ outF,
    u16* __restrict__ outH, u16* __restrict__ outH2, u16* __restrict__ outH3,
    int ntx, int N, int K) {
  constexpr int SLOT = 16384;
  const int tid = threadIdx.x;
  const int lane = tid & 63;
  const int wid = tid >> 6;
  const int wr = wid >> 2;   // 0..1 -> A half (slot select only)
  const int wc = wid & 3;    // 0..3 -> 32-col strip of the 128-col B tile

  // XCD-aware swizzle (grid %8==0 for all our launches)
  const int nwg = gridDim.x;
  int id = blockIdx.x;
  id = (id & 7) * (nwg >> 3) + (id >> 3);
  const int m0 = (id / ntx) * 256;
  const int n0 = (id % ntx) * 128;

  __shared__ __align__(16) char lds[5 * SLOT];

  f32x4 acc[8][2];
#pragma unroll
  for (int m = 0; m < 8; ++m)
#pragma unroll
    for (int n = 0; n < 2; ++n) acc[m][n] = (f32x4){0.f, 0.f, 0.f, 0.f};

  bf16x8 aR[2][2];   // one A-quarter (2 m-frags) at a time
  bf16x8 bR[2][2];   // both n-frags, held all tile

  // ---- hoisted LDS read offsets (k=0; k=1 is off^64 — bit 6 is disjoint
  //      from lq bits 4-5 and the slot base, and XOR distributes) ----
  int aOff[8], bOff[2];
  {
    const int lq = (lane >> 4) << 4;
#pragma unroll
    for (int m = 0; m < 8; ++m) {
      const int hr = m * 16 + (lane & 15);          // row within the 128-row A half
      aOff[m] = hr * 128 + (lq ^ ((hr & 7) << 4));
    }
#pragma unroll
    for (int n = 0; n < 2; ++n) {
      const int hr = wc * 32 + n * 16 + (lane & 15);
      bOff[n] = hr * 128 + (lq ^ ((hr & 7) << 4));
    }
  }

  // ---- hoisted stage addressing ----
  const int row0 = tid >> 3;                               // 0..63
  const int kb0  = ((tid & 7) * 16) ^ ((row0 & 7) << 4);   // inverse-swizzled src byte
  const size_t dRow = (size_t)128 * K;                     // +64 rows (bytes)
  const char* pA0 = (const char*)A + (size_t)(m0 + row0) * K * 2 + kb0;
  const char* pA1 = pA0 + (size_t)256 * K;                 // +128 rows
  const char* pB  = (const char*)B + (size_t)(n0 + row0) * K * 2 + kb0;
  const int ldst = tid * 16;                               // LDS offset within slot

#define STAGE(PTR, SB)                                                        \
  {                                                                           \
    gload_lds16(PTR, lds + (SB) + ldst);                                      \
    gload_lds16(PTR + dRow, lds + (SB) + ldst + 8192);                        \
    PTR += 128;                                                               \
  }

#define READA(SAB, Q)                                                         \
  _Pragma("unroll") for (int m2 = 0; m2 < 2; ++m2) {                          \
    const int _o = aOff[(Q) * 2 + m2];                                        \
    aR[m2][0] = *(const bf16x8*)(lds + (SAB) + _o);                           \
    aR[m2][1] = *(const bf16x8*)(lds + (SAB) + (_o ^ 64));                    \
  }

#define READB(SBB)                                                            \
  _Pragma("unroll") for (int n = 0; n < 2; ++n) {                             \
    const int _o = bOff[n];                                                   \
    bR[n][0] = *(const bf16x8*)(lds + (SBB) + _o);                            \
    bR[n][1] = *(const bf16x8*)(lds + (SBB) + (_o ^ 64));                     \
  }

#define MMAQ(Q)                                                               \
  __builtin_amdgcn_s_setprio(1);                                              \
  _Pragma("unroll") for (int m2 = 0; m2 < 2; ++m2)                            \
  _Pragma("unroll") for (int n = 0; n < 2; ++n)                               \
  _Pragma("unroll") for (int k = 0; k < 2; ++k)                               \
      acc[(Q) * 2 + m2][n] = __builtin_amdgcn_mfma_f32_16x16x32_bf16(         \
          aR[m2][k], bR[n][k], acc[(Q) * 2 + m2][n], 0, 0, 0);                \
  __builtin_amdgcn_s_setprio(0);

  const int NT = K >> 6;

  // prologue: tile0's halves {B,A0,A1} -> slots 0,1,2
  STAGE(pB,  0 * SLOT);
  STAGE(pA0, 1 * SLOT);
  STAGE(pA1, 2 * SLOT);
  asm volatile("s_waitcnt vmcnt(0)" ::: "memory");
  __builtin_amdgcn_s_barrier();

  int iB = 0;   // slot index of tile t's B half; advances +3 mod 5

  for (int t = 0; t < NT; ++t) {
    int ib1 = iB + 1 + wr; if (ib1 >= 5) ib1 -= 5;       // this wave's A slot
    const int sAb = __builtin_amdgcn_readfirstlane(ib1 * SLOT);
    const int sBb = __builtin_amdgcn_readfirstlane(iB * SLOT);
    int i0s = iB + 3; if (i0s >= 5) i0s -= 5;            // B(t+1)  -> dead A0(t-1)
    int i1s = iB + 4; if (i1s >= 5) i1s -= 5;            // A0(t+1) -> dead A1(t-1)
    const int s0 = i0s * SLOT, s1 = i1s * SLOT, s2 = iB * SLOT;  // A1(t+1) -> B(t)
    const bool st = (t < NT - 1);
    // ph0
    READB(sBb);
    READA(sAb, 0);
    if (st) STAGE(pB, s0);
    MMAQ(0);
    // ph1
    READA(sAb, 1);
    if (st) STAGE(pA0, s1);
    MMAQ(1);
    // ph2
    READA(sAb, 2);
    MMAQ(2);
    // mid barrier: all waves' B reads (ph0) complete before s2 overwrite
    __builtin_amdgcn_s_barrier();
    // ph3
    READA(sAb, 3);
    if (st) STAGE(pA1, s2);
    MMAQ(3);
    asm volatile("s_waitcnt vmcnt(0)" ::: "memory");
    __builtin_amdgcn_s_barrier();
    iB += 3; if (iB >= 5) iB -= 5;
  }

  // epilogue: C/D layout col = lane&15, row = (lane>>4)*4 + j
#pragma unroll
  for (int m = 0; m < 8; ++m) {
#pragma unroll
    for (int n = 0; n < 2; ++n) {
      const int col = n0 + wc * 32 + n * 16 + (lane & 15);
#pragma unroll
      for (int j = 0; j < 4; ++j) {
        const int row = m0 + wr * 128 + m * 16 + ((lane >> 4) << 2) + j;
        const float v = acc[m][n][j] + bias[col];
        if constexpr (EPI == 5) {
          const int rg = col >> 10;                     // block-uniform (128 | 1024)
          const size_t o = (size_t)row * 1024 + (col & 1023);
          if (rg == 0) outH[o] = f2bf(v);
          else if (rg == 1) outH2[o] = f2bf(v);
          else outH3[o] = f2bf(v);
        } else {
          const size_t o = (size_t)row * N + col;
          if constexpr (EPI == 2) {
            const float gt = bf2f(gate[o]);
            outF[o] = v * (gt / (1.f + __expf(-gt))) + resid[o];
          } else if constexpr (EPI == 6) {
            outH[o] = f2bf(v / (1.f + __expf(-v)));
          } else if constexpr (EPI == 7) {
            outH[o] = f2bf(v * bf2f(gate[o]));          // gate==outH ok (RAW per elem)
          } else if constexpr (EPI == 4) {
            outF[o] = v + outF[o];
          }
        }
      }
    }
  }
#undef STAGE
#undef READA
#undef READB
#undef MMAQ
}

extern "C" void kernel_launch(void* const* d_in, const int* in_sizes, int n_in,
                              void* d_out, int out_size, void* d_ws, size_t ws_size,
                              hipStream_t stream) {
  const float* x      = (const float*)d_in[0];
  const float* hidden = (const float*)d_in[1];
  const float* w_ln_z = (const float*)d_in[2];
  const float* b_ln_z = (const float*)d_in[3];
  const float* w_dt   = (const float*)d_in[4];
  const float* b_dt   = (const float*)d_in[5];
  const float* w_y    = (const float*)d_in[6];
  const float* b_y    = (const float*)d_in[7];
  const float* w_yg   = (const float*)d_in[8];
  const float* b_yg   = (const float*)d_in[9];
  const float* w_ff   = (const float*)d_in[10];
  const float* b_ff   = (const float*)d_in[11];
  const float* w_ffg  = (const float*)d_in[12];
  const float* b_ffg  = (const float*)d_in[13];
  const float* w_ffo  = (const float*)d_in[14];
  const float* b_ffo  = (const float*)d_in[15];
  const float* g_sio  = (const float*)d_in[16];
  const float* g_ffn  = (const float*)d_in[17];

  char* ws = (char*)d_ws;
  const size_t MB = 1ull << 20;
  u16*   WT_cat = (u16*)(ws + 0 * MB);      // 6 MiB  [3072][1024] (dt|lnz|yg)
  u16*   WT_y   = (u16*)(ws + 8 * MB);      // 2 MiB
  u16*   WT_ff  = (u16*)(ws + 10 * MB);     // 8 MiB  [4096][1024]
  u16*   WT_ffg = (u16*)(ws + 18 * MB);     // 8 MiB
  u16*   WT_ffo = (u16*)(ws + 26 * MB);     // 8 MiB  [1024][4096]
  float* b_cat  = (float*)(ws + 34 * MB);   // 12 KiB [3072]
  u16*   xn     = (u16*)(ws + 36 * MB);     // 32 MiB [16384][1024] bf16
  u16*   dt16   = (u16*)(ws + 68 * MB);     // 32 MiB bf16
  u16*   lnzb   = (u16*)(ws + 100 * MB);    // 32 MiB
  u16*   ygb    = (u16*)(ws + 132 * MB);    // 32 MiB
  u16*   hbf    = (u16*)(ws + 164 * MB);    // 32 MiB
  float* Pc     = (float*)(ws + 196 * MB);  // 1 MiB
  float* Sc     = (float*)(ws + 197 * MB);  // 1 MiB
  float* hin    = (float*)(ws + 198 * MB);  // 1 MiB
  u16*   gs     = (u16*)(ws + 68 * MB);     // 128 MiB overlay [16384][4096]
  // peak ws usage: 199 MiB

  float* x_out = (float*)d_out;
  float* h_out = (float*)d_out + (size_t)4 * 4096 * 1024;

  const int M = 16384, D = 1024, F = 4096;
  const dim3 tb(256);

  transpose_to_bf16<<<dim3(32, 32), tb, 0, stream>>>(w_dt, WT_cat, D, D);
  transpose_to_bf16<<<dim3(32, 32), tb, 0, stream>>>(w_ln_z, WT_cat + 1024 * 1024, D, D);
  transpose_to_bf16<<<dim3(32, 32), tb, 0, stream>>>(w_yg, WT_cat + 2 * 1024 * 1024, D, D);
  transpose_to_bf16<<<dim3(32, 32), tb, 0, stream>>>(w_y, WT_y, D, D);
  transpose_to_bf16<<<dim3(128, 32), tb, 0, stream>>>(w_ff, WT_ff, D, F);
  transpose_to_bf16<<<dim3(128, 32), tb, 0, stream>>>(w_ffg, WT_ffg, D, F);
  transpose_to_bf16<<<dim3(32, 128), tb, 0, stream>>>(w_ffo, WT_ffo, F, D);
  (void)hipMemcpyAsync(b_cat, b_dt, D * 4, hipMemcpyDeviceToDevice, stream);
  (void)hipMemcpyAsync(b_cat + 1024, b_ln_z, D * 4, hipMemcpyDeviceToDevice, stream);
  (void)hipMemcpyAsync(b_cat + 2048, b_yg, D * 4, hipMemcpyDeviceToDevice, stream);

  rmsnorm_kernel<<<M, tb, 0, stream>>>(x, g_sio, xn);

  // fused dt|lnz|yg GEMM: N=3072, ntx=24
  gemm256<5><<<dim3(64 * 24), 512, 0, stream>>>(xn, WT_cat, b_cat, nullptr, nullptr,
                                                nullptr, dt16, lnzb, ygb, 24, 3072, D);

  scan_pass1<<<1024, tb, 0, stream>>>(dt16, lnzb, Pc, Sc);
  scan_pass2<<<16, tb, 0, stream>>>(Pc, Sc, hidden, hin);
  scan_pass3<<<1024, tb, 0, stream>>>(dt16, lnzb, hin, h_out, hbf);

  // x1 = (h@w_y + b_y) * silu(yg) + x   (N=1024, ntx=8)
  gemm256<2><<<dim3(64 * 8), 512, 0, stream>>>(hbf, WT_y, b_y, ygb, x,
                                               x_out, nullptr, nullptr, nullptr, 8, D, D);

  rmsnorm_kernel<<<M, tb, 0, stream>>>(x_out, g_ffn, xn);

  // gs = silu(xn@w_ffg + b_ffg)   (N=4096, ntx=32)
  gemm256<6><<<dim3(64 * 32), 512, 0, stream>>>(xn, WT_ffg, b_ffg, nullptr, nullptr,
                                                nullptr, gs, nullptr, nullptr, 32, F, D);
  // gs = (xn@w_ff + b_ff) * gs   (in-place gated mul)
  gemm256<7><<<dim3(64 * 32), 512, 0, stream>>>(xn, WT_ff, b_ff, gs, nullptr,
                                                nullptr, gs, nullptr, nullptr, 32, F, D);
  // x_out += gs@w_ffo + b_ffo   (N=1024, ntx=8, K=4096)
  gemm256<4><<<dim3(64 * 8), 512, 0, stream>>>(gs, WT_ffo, b_ffo, nullptr, nullptr,
                                               x_out, nullptr, nullptr, nullptr, 8, D, F);
}

// Round 13
// 745.942 us; speedup vs baseline: 1.1047x; 1.0096x over previous
//
#include <hip/hip_runtime.h>
#include <cstdint>
#include <cstddef>

using u16 = unsigned short;
using bf16x8 = __attribute__((ext_vector_type(8))) short;
using f32x4  = __attribute__((ext_vector_type(4))) float;

__device__ __forceinline__ u16 f2bf(float f) {
  unsigned u = __float_as_uint(f);
  u += 0x7fffu + ((u >> 16) & 1u);
  return (u16)(u >> 16);
}
__device__ __forceinline__ float bf2f(u16 h) {
  return __uint_as_float(((unsigned)h) << 16);
}

__device__ __forceinline__ void gload_lds16(const void* g, void* l) {
  auto gp = reinterpret_cast<const __attribute__((address_space(1))) char*>(
      reinterpret_cast<uintptr_t>(g));
  auto lp = reinterpret_cast<__attribute__((address_space(3))) char*>(
      reinterpret_cast<uintptr_t>(l));
  __builtin_amdgcn_global_load_lds(gp, lp, 16, 0, 0);
}

// ---------- weight transpose + downcast: W f32[din][dout] -> WT bf16[dout][din]
__global__ __launch_bounds__(256) void transpose_to_bf16(
    const float* __restrict__ W, u16* __restrict__ WT, int din, int dout) {
  __shared__ float tile[32][33];
  const int j0 = blockIdx.x * 32;   // dout
  const int i0 = blockIdx.y * 32;   // din
  const int tx = threadIdx.x & 31;
  const int ty = threadIdx.x >> 5;  // 0..7
#pragma unroll
  for (int k = 0; k < 32; k += 8)
    tile[ty + k][tx] = W[(size_t)(i0 + ty + k) * dout + (j0 + tx)];
  __syncthreads();
#pragma unroll
  for (int k = 0; k < 32; k += 8)
    WT[(size_t)(j0 + ty + k) * din + (i0 + tx)] = f2bf(tile[tx][ty + k]);
}

// ---------- rmsnorm f32 -> bf16, one block per row of 1024
__global__ __launch_bounds__(256) void rmsnorm_kernel(
    const float* __restrict__ x, const float* __restrict__ g, u16* __restrict__ xn) {
  const int row = blockIdx.x;
  const float4 v = ((const float4*)(x + (size_t)row * 1024))[threadIdx.x];
  float ss = v.x * v.x + v.y * v.y + v.z * v.z + v.w * v.w;
#pragma unroll
  for (int off = 32; off > 0; off >>= 1) ss += __shfl_down(ss, off, 64);
  __shared__ float red[4];
  if ((threadIdx.x & 63) == 0) red[threadIdx.x >> 6] = ss;
  __syncthreads();
  const float rs = rsqrtf((red[0] + red[1] + red[2] + red[3]) * (1.f / 1024.f) + 1e-6f);
  const float4 gv = ((const float4*)g)[threadIdx.x];
  ushort4 o;
  o.x = f2bf(v.x * rs * gv.x);
  o.y = f2bf(v.y * rs * gv.y);
  o.z = f2bf(v.z * rs * gv.z);
  o.w = f2bf(v.w * rs * gv.w);
  ((ushort4*)(xn + (size_t)row * 1024))[threadIdx.x] = o;
}

// ---------- chunked linear-recurrence scan: h[l] = sig(-dt)*h[l-1] + sig(dt)*sig(lnz)
__global__ __launch_bounds__(256) void scan_pass1(
    const u16* __restrict__ dt, const u16* __restrict__ lnz,
    float* __restrict__ P, float* __restrict__ S) {
  const int blk = blockIdx.x;              // B*64*4 = 1024 blocks
  const int dblk = blk & 3;
  const int chunk = (blk >> 2) & 63;
  const int b = blk >> 8;
  const int d = dblk * 256 + threadIdx.x;
  const size_t base = ((size_t)b * 4096 + (size_t)chunk * 64) * 1024 + d;
  float p = 1.f, s = 0.f;
#pragma unroll 8
  for (int l = 0; l < 64; ++l) {
    const float dtv = bf2f(dt[base + (size_t)l * 1024]);
    const float zv = bf2f(lnz[base + (size_t)l * 1024]);
    const float a = 1.f / (1.f + __expf(dtv));        // sigmoid(-dt)
    const float zs = 1.f / (1.f + __expf(-zv));       // sigmoid(lnz_pre)
    const float in = (1.f - a) * zs;
    p *= a;
    s = a * s + in;
  }
  const size_t o = ((size_t)b * 64 + chunk) * 1024 + d;
  P[o] = p;
  S[o] = s;
}

__global__ __launch_bounds__(256) void scan_pass2(
    const float* __restrict__ P, const float* __restrict__ S,
    const float* __restrict__ hidden, float* __restrict__ hin) {
  const int idx = blockIdx.x * 256 + threadIdx.x;  // 0..4095
  const int b = idx >> 10, d = idx & 1023;
  float h = hidden[idx];
#pragma unroll 8
  for (int c = 0; c < 64; ++c) {
    const size_t o = ((size_t)b * 64 + c) * 1024 + d;
    hin[o] = h;
    h = P[o] * h + S[o];
  }
}

__global__ __launch_bounds__(256) void scan_pass3(
    const u16* __restrict__ dt, const u16* __restrict__ lnz,
    const float* __restrict__ hin, float* __restrict__ h_out, u16* __restrict__ hbf) {
  const int blk = blockIdx.x;
  const int dblk = blk & 3;
  const int chunk = (blk >> 2) & 63;
  const int b = blk >> 8;
  const int d = dblk * 256 + threadIdx.x;
  const size_t base = ((size_t)b * 4096 + (size_t)chunk * 64) * 1024 + d;
  float h = hin[((size_t)b * 64 + chunk) * 1024 + d];
#pragma unroll 4
  for (int l = 0; l < 64; ++l) {
    const float dtv = bf2f(dt[base + (size_t)l * 1024]);
    const float zv = bf2f(lnz[base + (size_t)l * 1024]);
    const float a = 1.f / (1.f + __expf(dtv));
    const float zs = 1.f / (1.f + __expf(-zv));
    h = a * h + (1.f - a) * zs;
    h_out[base + (size_t)l * 1024] = h;
    hbf[base + (size_t)l * 1024] = f2bf(h);
  }
}

// ---------- 256x128 GEMM, 2 blocks/CU, 4Mx2N waves: C = A[M][K] @ B^T (bf16).
// R12 TLP structure (80 KiB ring-5, <=128 VGPR, 2 independent blocks/CU)
// with the wave grid changed 2Mx4N -> 4Mx2N (wave tile 64x64):
// per-wave LDS reads drop 20 -> 16 ds_read_b128 (A 8 + B 8), block total
// 160 KB -> 128 KB per K-tile (-20%) — LDS read service was the largest
// budget item (~65% busy at R12).
// Wave wid: wrow = wid>>1 (0..3, 64-row strip), wcol = wid&1 (64-col strip);
// A-half slot = wrow>>1, strip within half = (wrow&1)*64.
// Ring (slot = h%5), unchanged audit from R12:
//  - stage B(t+1)  -> dead A0(t-1)   [ph0]
//  - stage A0(t+1) -> dead A1(t-1)   [ph1]
//  - stage A1(t+1) -> B(t) slot, post-midbar (B reads consumed in ph0) [ph3]
//  - vmcnt(0)+barrier at tile end -> t+1 resident.
// EPI: 5 = fused3: bf16 outs {outH=dt, outH2=lnz, outH3=yg}, row stride 1024
//      2 = f32 out = (acc+b)*silu(gate bf16) + resid
//      6 = bf16 out = silu(acc+b)
//      7 = bf16 out = (acc+b)*bf2f(gate)   (gate may alias outH: in-place)
//      4 = f32 out = acc + b + outF (in-place residual add)
template <int EPI>
__global__ __launch_bounds__(512, 4) void gemm256(
    const u16* __restrict__ A, const u16* __restrict__ B,
    const float* __restrict__ bias, const u16* __restrict__ gate,
    const float* __restrict__ resid, float* __restrict__ outF,
    u16* __restrict__ outH, u16* __restrict__ outH2, u16* __restrict__ outH3,
    int ntx, int N, int K) {
  constexpr int SLOT = 16384;
  const int tid = threadIdx.x;
  const int lane = tid & 63;
  const int wid = tid >> 6;
  const int wrow = wid >> 1;   // 0..3 -> 64-row strip of the 256-row tile
  const int wcol = wid & 1;    // 0..1 -> 64-col strip of the 128-col tile
  const int whalf = wrow >> 1; // A-half slot select
  const int wsub  = wrow & 1;  // 64-row strip within the 128-row half

  // XCD-aware swizzle (grid %8==0 for all our launches)
  const int nwg = gridDim.x;
  int id = blockIdx.x;
  id = (id & 7) * (nwg >> 3) + (id >> 3);
  const int m0 = (id / ntx) * 256;
  const int n0 = (id % ntx) * 128;

  __shared__ __align__(16) char lds[5 * SLOT];

  f32x4 acc[4][4];   // [m-frag][n-frag] over the wave's 64x64 tile
#pragma unroll
  for (int m = 0; m < 4; ++m)
#pragma unroll
    for (int n = 0; n < 4; ++n) acc[m][n] = (f32x4){0.f, 0.f, 0.f, 0.f};

  bf16x8 aR[2];      // one m-frag (2 k) at a time
  bf16x8 bR[4][2];   // all 4 n-frags, held all tile

  // ---- hoisted LDS read offsets (k=0; k=1 via ^64 — bit 6 disjoint from
  //      the lq bits 4-5 and the swizzle bits) ----
  int aOff[4], bOff[4];
  {
    const int lq = (lane >> 4) << 4;
#pragma unroll
    for (int m = 0; m < 4; ++m) {
      const int hr = wsub * 64 + m * 16 + (lane & 15);  // row within 128-row A half
      aOff[m] = hr * 128 + (lq ^ ((hr & 7) << 4));
    }
#pragma unroll
    for (int n = 0; n < 4; ++n) {
      const int hr = wcol * 64 + n * 16 + (lane & 15);  // row within 128-row B slot
      bOff[n] = hr * 128 + (lq ^ ((hr & 7) << 4));
    }
  }

  // ---- hoisted stage addressing ----
  const int row0 = tid >> 3;                               // 0..63
  const int kb0  = ((tid & 7) * 16) ^ ((row0 & 7) << 4);   // inverse-swizzled src byte
  const size_t dRow = (size_t)128 * K;                     // +64 rows (bytes)
  const char* pA0 = (const char*)A + (size_t)(m0 + row0) * K * 2 + kb0;
  const char* pA1 = pA0 + (size_t)256 * K;                 // +128 rows
  const char* pB  = (const char*)B + (size_t)(n0 + row0) * K * 2 + kb0;
  const int ldst = tid * 16;                               // LDS offset within slot

#define STAGE(PTR, SB)                                                        \
  {                                                                           \
    gload_lds16(PTR, lds + (SB) + ldst);                                      \
    gload_lds16(PTR + dRow, lds + (SB) + ldst + 8192);                        \
    PTR += 128;                                                               \
  }

#define READA(SAB, Q)                                                         \
  {                                                                           \
    const int _o = aOff[Q];                                                   \
    aR[0] = *(const bf16x8*)(lds + (SAB) + _o);                               \
    aR[1] = *(const bf16x8*)(lds + (SAB) + (_o ^ 64));                        \
  }

#define READB(SBB)                                                            \
  _Pragma("unroll") for (int n = 0; n < 4; ++n) {                             \
    const int _o = bOff[n];                                                   \
    bR[n][0] = *(const bf16x8*)(lds + (SBB) + _o);                            \
    bR[n][1] = *(const bf16x8*)(lds + (SBB) + (_o ^ 64));                     \
  }

#define MMAQ(Q)                                                               \
  __builtin_amdgcn_s_setprio(1);                                              \
  _Pragma("unroll") for (int n = 0; n < 4; ++n)                               \
  _Pragma("unroll") for (int k = 0; k < 2; ++k)                               \
      acc[Q][n] = __builtin_amdgcn_mfma_f32_16x16x32_bf16(                    \
          aR[k], bR[n][k], acc[Q][n], 0, 0, 0);                               \
  __builtin_amdgcn_s_setprio(0);

  const int NT = K >> 6;

  // prologue: tile0's halves {B,A0,A1} -> slots 0,1,2
  STAGE(pB,  0 * SLOT);
  STAGE(pA0, 1 * SLOT);
  STAGE(pA1, 2 * SLOT);
  asm volatile("s_waitcnt vmcnt(0)" ::: "memory");
  __builtin_amdgcn_s_barrier();

  int iB = 0;   // slot index of tile t's B half; advances +3 mod 5

  for (int t = 0; t < NT; ++t) {
    int ib1 = iB + 1 + whalf; if (ib1 >= 5) ib1 -= 5;    // this wave's A slot
    const int sAb = __builtin_amdgcn_readfirstlane(ib1 * SLOT);
    const int sBb = __builtin_amdgcn_readfirstlane(iB * SLOT);
    int i0s = iB + 3; if (i0s >= 5) i0s -= 5;            // B(t+1)  -> dead A0(t-1)
    int i1s = iB + 4; if (i1s >= 5) i1s -= 5;            // A0(t+1) -> dead A1(t-1)
    const int s0 = i0s * SLOT, s1 = i1s * SLOT, s2 = iB * SLOT;  // A1(t+1) -> B(t)
    const bool st = (t < NT - 1);
    // ph0
    READB(sBb);
    READA(sAb, 0);
    if (st) STAGE(pB, s0);
    MMAQ(0);
    // ph1
    READA(sAb, 1);
    if (st) STAGE(pA0, s1);
    MMAQ(1);
    // ph2
    READA(sAb, 2);
    MMAQ(2);
    // mid barrier: all waves' B reads (ph0, reg-consumed) precede s2 overwrite
    __builtin_amdgcn_s_barrier();
    // ph3
    READA(sAb, 3);
    if (st) STAGE(pA1, s2);
    MMAQ(3);
    asm volatile("s_waitcnt vmcnt(0)" ::: "memory");
    __builtin_amdgcn_s_barrier();
    iB += 3; if (iB >= 5) iB -= 5;
  }

  // epilogue: C/D layout col = lane&15, row = (lane>>4)*4 + j
#pragma unroll
  for (int m = 0; m < 4; ++m) {
#pragma unroll
    for (int n = 0; n < 4; ++n) {
      const int col = n0 + wcol * 64 + n * 16 + (lane & 15);
#pragma unroll
      for (int j = 0; j < 4; ++j) {
        const int row = m0 + wrow * 64 + m * 16 + ((lane >> 4) << 2) + j;
        const float v = acc[m][n][j] + bias[col];
        if constexpr (EPI == 5) {
          const int rg = col >> 10;                     // block-uniform
          const size_t o = (size_t)row * 1024 + (col & 1023);
          if (rg == 0) outH[o] = f2bf(v);
          else if (rg == 1) outH2[o] = f2bf(v);
          else outH3[o] = f2bf(v);
        } else {
          const size_t o = (size_t)row * N + col;
          if constexpr (EPI == 2) {
            const float gt = bf2f(gate[o]);
            outF[o] = v * (gt / (1.f + __expf(-gt))) + resid[o];
          } else if constexpr (EPI == 6) {
            outH[o] = f2bf(v / (1.f + __expf(-v)));
          } else if constexpr (EPI == 7) {
            outH[o] = f2bf(v * bf2f(gate[o]));          // gate==outH ok (RAW per elem)
          } else if constexpr (EPI == 4) {
            outF[o] = v + outF[o];
          }
        }
      }
    }
  }
#undef STAGE
#undef READA
#undef READB
#undef MMAQ
}

extern "C" void kernel_launch(void* const* d_in, const int* in_sizes, int n_in,
                              void* d_out, int out_size, void* d_ws, size_t ws_size,
                              hipStream_t stream) {
  const float* x      = (const float*)d_in[0];
  const float* hidden = (const float*)d_in[1];
  const float* w_ln_z = (const float*)d_in[2];
  const float* b_ln_z = (const float*)d_in[3];
  const float* w_dt   = (const float*)d_in[4];
  const float* b_dt   = (const float*)d_in[5];
  const float* w_y    = (const float*)d_in[6];
  const float* b_y    = (const float*)d_in[7];
  const float* w_yg   = (const float*)d_in[8];
  const float* b_yg   = (const float*)d_in[9];
  const float* w_ff   = (const float*)d_in[10];
  const float* b_ff   = (const float*)d_in[11];
  const float* w_ffg  = (const float*)d_in[12];
  const float* b_ffg  = (const float*)d_in[13];
  const float* w_ffo  = (const float*)d_in[14];
  const float* b_ffo  = (const float*)d_in[15];
  const float* g_sio  = (const float*)d_in[16];
  const float* g_ffn  = (const float*)d_in[17];

  char* ws = (char*)d_ws;
  const size_t MB = 1ull << 20;
  u16*   WT_cat = (u16*)(ws + 0 * MB);      // 6 MiB  [3072][1024] (dt|lnz|yg)
  u16*   WT_y   = (u16*)(ws + 8 * MB);      // 2 MiB
  u16*   WT_ff  = (u16*)(ws + 10 * MB);     // 8 MiB  [4096][1024]
  u16*   WT_ffg = (u16*)(ws + 18 * MB);     // 8 MiB
  u16*   WT_ffo = (u16*)(ws + 26 * MB);     // 8 MiB  [1024][4096]
  float* b_cat  = (float*)(ws + 34 * MB);   // 12 KiB [3072]
  u16*   xn     = (u16*)(ws + 36 * MB);     // 32 MiB [16384][1024] bf16
  u16*   dt16   = (u16*)(ws + 68 * MB);     // 32 MiB bf16
  u16*   lnzb   = (u16*)(ws + 100 * MB);    // 32 MiB
  u16*   ygb    = (u16*)(ws + 132 * MB);    // 32 MiB
  u16*   hbf    = (u16*)(ws + 164 * MB);    // 32 MiB
  float* Pc     = (float*)(ws + 196 * MB);  // 1 MiB
  float* Sc     = (float*)(ws + 197 * MB);  // 1 MiB
  float* hin    = (float*)(ws + 198 * MB);  // 1 MiB
  u16*   gs     = (u16*)(ws + 68 * MB);     // 128 MiB overlay [16384][4096]
  // peak ws usage: 199 MiB

  float* x_out = (float*)d_out;
  float* h_out = (float*)d_out + (size_t)4 * 4096 * 1024;

  const int M = 16384, D = 1024, F = 4096;
  const dim3 tb(256);

  transpose_to_bf16<<<dim3(32, 32), tb, 0, stream>>>(w_dt, WT_cat, D, D);
  transpose_to_bf16<<<dim3(32, 32), tb, 0, stream>>>(w_ln_z, WT_cat + 1024 * 1024, D, D);
  transpose_to_bf16<<<dim3(32, 32), tb, 0, stream>>>(w_yg, WT_cat + 2 * 1024 * 1024, D, D);
  transpose_to_bf16<<<dim3(32, 32), tb, 0, stream>>>(w_y, WT_y, D, D);
  transpose_to_bf16<<<dim3(128, 32), tb, 0, stream>>>(w_ff, WT_ff, D, F);
  transpose_to_bf16<<<dim3(128, 32), tb, 0, stream>>>(w_ffg, WT_ffg, D, F);
  transpose_to_bf16<<<dim3(32, 128), tb, 0, stream>>>(w_ffo, WT_ffo, F, D);
  (void)hipMemcpyAsync(b_cat, b_dt, D * 4, hipMemcpyDeviceToDevice, stream);
  (void)hipMemcpyAsync(b_cat + 1024, b_ln_z, D * 4, hipMemcpyDeviceToDevice, stream);
  (void)hipMemcpyAsync(b_cat + 2048, b_yg, D * 4, hipMemcpyDeviceToDevice, stream);

  rmsnorm_kernel<<<M, tb, 0, stream>>>(x, g_sio, xn);

  // fused dt|lnz|yg GEMM: N=3072, ntx=24
  gemm256<5><<<dim3(64 * 24), 512, 0, stream>>>(xn, WT_cat, b_cat, nullptr, nullptr,
                                                nullptr, dt16, lnzb, ygb, 24, 3072, D);

  scan_pass1<<<1024, tb, 0, stream>>>(dt16, lnzb, Pc, Sc);
  scan_pass2<<<16, tb, 0, stream>>>(Pc, Sc, hidden, hin);
  scan_pass3<<<1024, tb, 0, stream>>>(dt16, lnzb, hin, h_out, hbf);

  // x1 = (h@w_y + b_y) * silu(yg) + x   (N=1024, ntx=8)
  gemm256<2><<<dim3(64 * 8), 512, 0, stream>>>(hbf, WT_y, b_y, ygb, x,
                                               x_out, nullptr, nullptr, nullptr, 8, D, D);

  rmsnorm_kernel<<<M, tb, 0, stream>>>(x_out, g_ffn, xn);

  // gs = silu(xn@w_ffg + b_ffg)   (N=4096, ntx=32)
  gemm256<6><<<dim3(64 * 32), 512, 0, stream>>>(xn, WT_ffg, b_ffg, nullptr, nullptr,
                                                nullptr, gs, nullptr, nullptr, 32, F, D);
  // gs = (xn@w_ff + b_ff) * gs   (in-place gated mul)
  gemm256<7><<<dim3(64 * 32), 512, 0, stream>>>(xn, WT_ff, b_ff, gs, nullptr,
                                                nullptr, gs, nullptr, nullptr, 32, F, D);
  // x_out += gs@w_ffo + b_ffo   (N=1024, ntx=8, K=4096)
  gemm256<4><<<dim3(64 * 8), 512, 0, stream>>>(gs, WT_ffo, b_ffo, nullptr, nullptr,
                                               x_out, nullptr, nullptr, nullptr, 8, D, F);
}